// Round 8
// baseline (455.654 us; speedup 1.0000x reference)
//
#include <hip/hip_runtime.h>

#define BATCH 16
#define NPTS 1024
#define CIN 16
#define NODES (BATCH*NPTS)      // 16384
#define KNN 10
#define EDGES (NODES*KNN)       // 163840
#define JCH 16                  // j-chunks for KNN
#define JLEN (NPTS/JCH)         // 64

typedef unsigned short ushort_t;
typedef __attribute__((ext_vector_type(8))) short bf16x8;
typedef __attribute__((ext_vector_type(4))) float f32x4;

__device__ __forceinline__ int uclamp(int v, int hi) {
    return ((unsigned)v > (unsigned)hi) ? hi : v;
}
__device__ __forceinline__ float bf2f(ushort_t u) {
    union { unsigned int i; float f; } v; v.i = ((unsigned int)u) << 16; return v.f;
}
__device__ __forceinline__ ushort_t f2bf(float f) {
    union { float f; unsigned int i; } v; v.f = f;
    unsigned int r = (v.i + 0x7fffu + ((v.i >> 16) & 1u)) >> 16;
    return (ushort_t)r;
}

// ---------------- cast layer-1..3 weights f32 -> bf16 (229376 elems) ----------------
__global__ __launch_bounds__(256) void cast_weights(const float* __restrict__ s0,
                                                    const float* __restrict__ s1,
                                                    const float* __restrict__ s2,
                                                    const float* __restrict__ s3,
                                                    const float* __restrict__ s4,
                                                    const float* __restrict__ s5,
                                                    ushort_t* __restrict__ dst) {
    int t = blockIdx.x * 256 + threadIdx.x;   // 896 blocks
    const float* s; int off;
    if      (t <  32768) { s = s0; off = 0; }
    else if (t <  65536) { s = s1; off = 32768; }
    else if (t < 131072) { s = s2; off = 65536; }
    else if (t < 196608) { s = s3; off = 131072; }
    else if (t < 212992) { s = s4; off = 196608; }
    else                 { s = s5; off = 212992; }
    dst[t] = f2bf(s[t - off]);
}

// ---------------- KNN phase A: per-(i, j-chunk) top-10, depth-3 parallel insert ----------------
// grid dim3(JCH, 4, BATCH) = 1024 blocks, 256 threads; thread = node i, block covers 64 j's.
__global__ __launch_bounds__(256, 4) void knn_partial(const float* __restrict__ xf,
                                                      float* __restrict__ pd,
                                                      int* __restrict__ pi_) {
    __shared__ float xs[JLEN * 16];   // 4 KB
    __shared__ float sq[JLEN];
    int jc = blockIdx.x, ic = blockIdx.y, b = blockIdx.z;
    int tid = threadIdx.x;
    int i_local = (ic << 8) | tid;
    const float* xbp = xf + (size_t)b * NPTS * CIN;

    const float4* xip = (const float4*)(xbp + i_local * 16);
    float4 xa = xip[0], xb4 = xip[1], xc = xip[2], xd = xip[3];
    float sqi = xa.x*xa.x + xa.y*xa.y + xa.z*xa.z + xa.w*xa.w
              + xb4.x*xb4.x + xb4.y*xb4.y + xb4.z*xb4.z + xb4.w*xb4.w
              + xc.x*xc.x + xc.y*xc.y + xc.z*xc.z + xc.w*xc.w
              + xd.x*xd.x + xd.y*xd.y + xd.z*xd.z + xd.w*xd.w;

    int jbase = jc * JLEN;
    {   // stage 64 rows: thread t stages quarter (t&3) of row (t>>2)
        int row = tid >> 2, q = tid & 3;
        ((float4*)(xs + row * 16))[q] = *(const float4*)(xbp + (jbase + row) * 16 + q * 4);
    }
    __syncthreads();
    if (tid < JLEN) {
        const float4* rp = (const float4*)(xs + tid * 16);
        float4 a = rp[0], bq = rp[1], c4 = rp[2], d4 = rp[3];
        sq[tid] = a.x*a.x + a.y*a.y + a.z*a.z + a.w*a.w
                + bq.x*bq.x + bq.y*bq.y + bq.z*bq.z + bq.w*bq.w
                + c4.x*c4.x + c4.y*c4.y + c4.z*c4.z + c4.w*c4.w
                + d4.x*d4.x + d4.y*d4.y + d4.z*d4.z + d4.w*d4.w;
    }
    __syncthreads();

    float bd[10]; int bi[10];
#pragma unroll
    for (int r = 0; r < 10; ++r) { bd[r] = 3.0e38f; bi[r] = 0; }

#pragma unroll 2
    for (int jl = 0; jl < JLEN; ++jl) {
        const float4* yp = (const float4*)(xs + jl * 16);
        float4 ya = yp[0], yb = yp[1], yc = yp[2], yd = yp[3];
        float d0 = ya.x*xa.x  + ya.y*xa.y  + ya.z*xa.z  + ya.w*xa.w;
        float d1 = yb.x*xb4.x + yb.y*xb4.y + yb.z*xb4.z + yb.w*xb4.w;
        float d2 = yc.x*xc.x  + yc.y*xc.y  + yc.z*xc.z  + yc.w*xc.w;
        float d3 = yd.x*xd.x  + yd.y*xd.y  + yd.z*xd.z  + yd.w*xd.w;
        float dot = (d0 + d1) + (d2 + d3);
        int j = jbase + jl;
        float dist = (sqi + sq[jl]) - 2.0f * dot;
        float c = (j != i_local) ? dist : 3.0e38f;
        int cj = j;
        // parallel sorted-insert: all compares on OLD bd (depth ~3, not ~40)
        bool m[10];
#pragma unroll
        for (int k = 0; k < 10; ++k) m[k] = c < bd[k];
        float nbd[10]; int nbi[10];
        nbd[0] = fminf(c, bd[0]);
        nbi[0] = m[0] ? cj : bi[0];
#pragma unroll
        for (int k = 1; k < 10; ++k) {
            nbd[k] = fminf(fmaxf(c, bd[k-1]), bd[k]);   // med3(c, bd[k-1], bd[k])
            nbi[k] = m[k] ? (m[k-1] ? bi[k-1] : cj) : bi[k];
        }
#pragma unroll
        for (int k = 0; k < 10; ++k) { bd[k] = nbd[k]; bi[k] = nbi[k]; }
    }
    int base = (((b * JCH + jc) * NPTS) + i_local) * 10;
#pragma unroll
    for (int r = 0; r < 10; ++r) { pd[base + r] = bd[r]; pi_[base + r] = bi[r]; }
}

// ---------------- KNN phase B: merge JCH sorted 10-lists per node + zero cnt/cur ----------------
// 256 blocks x 64 threads = 16384 nodes.
__global__ __launch_bounds__(64) void knn_merge(const float* __restrict__ pd,
                                                const int* __restrict__ pi_,
                                                int* __restrict__ nbors,
                                                int* __restrict__ cntz) {
    int t = blockIdx.x * 64 + threadIdx.x;
    // fold-in: zero cnt+cur (32768 ints = 8192 int4) using first 128 blocks
    if (t < 8192) ((int4*)cntz)[t] = make_int4(0, 0, 0, 0);
    int b = t >> 10, i = t & 1023;
    float bd[10]; int bi[10];
#pragma unroll
    for (int r = 0; r < 10; ++r) { bd[r] = 3.0e38f; bi[r] = 0; }
    for (int jc = 0; jc < JCH; ++jc) {
        int base = (((b * JCH + jc) * NPTS) + i) * 10;
        for (int r = 0; r < 10; ++r) {
            float cd = pd[base + r];
            if (!(cd < bd[9])) break;             // chunk list ascending -> done
            int ci = pi_[base + r];
#pragma unroll
            for (int q = 0; q < 10; ++q) {
                if (cd < bd[q]) {
                    float td = bd[q]; int ti = bi[q];
                    bd[q] = cd; bi[q] = ci;
                    cd = td; ci = ti;
                }
            }
        }
    }
    int gi = b * NPTS + i;
#pragma unroll
    for (int r = 0; r < 10; ++r)
        nbors[gi * KNN + r] = b * NPTS + uclamp(bi[r], NPTS - 1);
}

// ---------------- reverse-CSR build ----------------
__global__ __launch_bounds__(256) void count_kernel(const int* __restrict__ nbors,
                                                    int* __restrict__ cnt) {
    int e = blockIdx.x * 256 + threadIdx.x;
    if (e < EDGES) atomicAdd(&cnt[uclamp(nbors[e], NODES - 1)], 1);
}

__global__ __launch_bounds__(256) void scan_kernel(const int* __restrict__ cnt,
                                                   int* __restrict__ rs) {
    __shared__ int part[256];
    int t = threadIdx.x;
    int base = t << 6;
    int s = 0;
    for (int u = 0; u < 64; ++u) s += cnt[base + u];
    part[t] = s;
    __syncthreads();
    for (int off = 1; off < 256; off <<= 1) {
        int v = (t >= off) ? part[t - off] : 0;
        __syncthreads();
        part[t] += v;
        __syncthreads();
    }
    int run = part[t] - s;
    for (int u = 0; u < 64; ++u) { rs[base + u] = run; run += cnt[base + u]; }
    if (t == 255) rs[NODES] = run;
}

__global__ __launch_bounds__(256) void fill_kernel(const int* __restrict__ nbors,
                                                   const int* __restrict__ rs,
                                                   int* __restrict__ cur,
                                                   int* __restrict__ esrc) {
    int e = blockIdx.x * 256 + threadIdx.x;
    if (e < EDGES) {
        int dst = uclamp(nbors[e], NODES - 1);
        int src = e / 10;
        int pos = atomicAdd(&cur[dst], 1);
        esrc[uclamp(rs[dst] + pos, EDGES - 1)] = src;
    }
}

// ---------------- aggregation f32 (layer 0, din=16) ----------------
__global__ __launch_bounds__(256) void agg_kernel(const float* __restrict__ hin,
                                                  float* __restrict__ agg,
                                                  const int* __restrict__ rs,
                                                  const int* __restrict__ esrc,
                                                  int din, int sh) {
    int gid = blockIdx.x * 256 + threadIdx.x;
    int n = gid >> sh;
    int c = (gid & ((1 << sh) - 1)) << 2;
    int e1 = uclamp(rs[n + 1], EDGES);
    int e0 = uclamp(rs[n], e1);
    float4 acc = {0.f, 0.f, 0.f, 0.f};
    for (int e = e0; e < e1; ++e) {
        int s = uclamp(esrc[e], NODES - 1);
        float4 v = *(const float4*)(hin + (size_t)s * din + c);
        acc.x += v.x; acc.y += v.y; acc.z += v.z; acc.w += v.w;
    }
    *(float4*)(agg + (size_t)n * din + c) = acc;
}

// ---------------- aggregation bf16 (layers 1-3) ----------------
__global__ __launch_bounds__(256) void agg_bf16(const ushort_t* __restrict__ hin,
                                                ushort_t* __restrict__ agg,
                                                const int* __restrict__ rs,
                                                const int* __restrict__ esrc,
                                                int din, int sh) {
    int gid = blockIdx.x * 256 + threadIdx.x;
    int n = gid >> sh;
    int c = (gid & ((1 << sh) - 1)) << 2;
    int e1 = uclamp(rs[n + 1], EDGES);
    int e0 = uclamp(rs[n], e1);
    float a0 = 0.f, a1 = 0.f, a2 = 0.f, a3 = 0.f;
    for (int e = e0; e < e1; ++e) {
        int s = uclamp(esrc[e], NODES - 1);
        ushort4 v = *(const ushort4*)(hin + (size_t)s * din + c);
        a0 += bf2f(v.x); a1 += bf2f(v.y); a2 += bf2f(v.z); a3 += bf2f(v.w);
    }
    ushort4 o; o.x = f2bf(a0); o.y = f2bf(a1); o.z = f2bf(a2); o.w = f2bf(a3);
    *(ushort4*)(agg + (size_t)n * din + c) = o;
}

// ---------------- layer-0 GEMM (f32 vector, K=16), bf16 out ----------------
__global__ __launch_bounds__(256) void gemm_layer0(const float* __restrict__ A1,
                                                   const float* __restrict__ A2,
                                                   const float* __restrict__ W1,
                                                   const float* __restrict__ W2,
                                                   const float* __restrict__ bias,
                                                   ushort_t* __restrict__ Out,
                                                   int Kdim, int Ndim) {
    __shared__ float As1[16 * 64], As2[16 * 64], Bs1[16 * 64], Bs2[16 * 64];
    int tid = threadIdx.x;
    int m0 = blockIdx.y * 64;
    int n0 = blockIdx.x * 64;
    int tx = tid & 15, ty = tid >> 4;
    int lr = tid >> 2;
    int lc = (tid & 3) << 2;
    float acc[4][4] = {};

    for (int k0 = 0; k0 < Kdim; k0 += 16) {
        __syncthreads();
        {
            float4 a = *(const float4*)(A1 + (size_t)(m0 + lr) * Kdim + k0 + lc);
            As1[(lc + 0) * 64 + lr] = a.x; As1[(lc + 1) * 64 + lr] = a.y;
            As1[(lc + 2) * 64 + lr] = a.z; As1[(lc + 3) * 64 + lr] = a.w;
            float4 b = *(const float4*)(A2 + (size_t)(m0 + lr) * Kdim + k0 + lc);
            As2[(lc + 0) * 64 + lr] = b.x; As2[(lc + 1) * 64 + lr] = b.y;
            As2[(lc + 2) * 64 + lr] = b.z; As2[(lc + 3) * 64 + lr] = b.w;
            float4 w1 = *(const float4*)(W1 + (size_t)(n0 + lr) * Kdim + k0 + lc);
            Bs1[(lc + 0) * 64 + lr] = w1.x; Bs1[(lc + 1) * 64 + lr] = w1.y;
            Bs1[(lc + 2) * 64 + lr] = w1.z; Bs1[(lc + 3) * 64 + lr] = w1.w;
            float4 w2 = *(const float4*)(W2 + (size_t)(n0 + lr) * Kdim + k0 + lc);
            Bs2[(lc + 0) * 64 + lr] = w2.x; Bs2[(lc + 1) * 64 + lr] = w2.y;
            Bs2[(lc + 2) * 64 + lr] = w2.z; Bs2[(lc + 3) * 64 + lr] = w2.w;
        }
        __syncthreads();
#pragma unroll
        for (int k = 0; k < 16; ++k) {
            float4 a1 = *(const float4*)(As1 + k * 64 + (ty << 2));
            float4 a2 = *(const float4*)(As2 + k * 64 + (ty << 2));
            float4 b1 = *(const float4*)(Bs1 + k * 64 + (tx << 2));
            float4 b2 = *(const float4*)(Bs2 + k * 64 + (tx << 2));
            float av1[4] = {a1.x, a1.y, a1.z, a1.w};
            float av2[4] = {a2.x, a2.y, a2.z, a2.w};
            float bv1[4] = {b1.x, b1.y, b1.z, b1.w};
            float bv2[4] = {b2.x, b2.y, b2.z, b2.w};
#pragma unroll
            for (int u = 0; u < 4; ++u)
#pragma unroll
                for (int v = 0; v < 4; ++v)
                    acc[u][v] += av1[u] * bv1[v] + av2[u] * bv2[v];
        }
    }
    float bv[4];
#pragma unroll
    for (int v = 0; v < 4; ++v) bv[v] = bias[n0 + (tx << 2) + v];
#pragma unroll
    for (int u = 0; u < 4; ++u) {
        int m = m0 + (ty << 2) + u;
        ushort4 o;
        o.x = f2bf(fmaxf(acc[u][0] + bv[0], 0.f));
        o.y = f2bf(fmaxf(acc[u][1] + bv[1], 0.f));
        o.z = f2bf(fmaxf(acc[u][2] + bv[2], 0.f));
        o.w = f2bf(fmaxf(acc[u][3] + bv[3], 0.f));
        *(ushort4*)(Out + (size_t)m * Ndim + n0 + (tx << 2)) = o;
    }
}

// ---------------- MFMA dual-GEMM (layers 1-3) ----------------
// mode 1: bf16 out to outp. mode 2: split hi/lo bf16 to outp/outp2 (for final Gram).
__global__ __launch_bounds__(256) void gemm_mfma(const ushort_t* __restrict__ A1,
                                                 const ushort_t* __restrict__ A2,
                                                 const ushort_t* __restrict__ W1,
                                                 const ushort_t* __restrict__ W2,
                                                 const float* __restrict__ bias,
                                                 ushort_t* __restrict__ outp,
                                                 ushort_t* __restrict__ outp2,
                                                 int Kdim, int Ndim, int relu, int mode) {
    int tid = threadIdx.x;
    int wave = tid >> 6, lane = tid & 63;
    int quad = lane >> 4, l16 = lane & 15;
    int ms = blockIdx.y * 64 + wave * 16;
    int n0 = blockIdx.x * 64;

    f32x4 acc0 = {0.f,0.f,0.f,0.f}, acc1 = acc0, acc2 = acc0, acc3 = acc0;
    const ushort_t* a1p = A1 + (size_t)(ms + l16) * Kdim + quad * 8;
    const ushort_t* a2p = A2 + (size_t)(ms + l16) * Kdim + quad * 8;
    const ushort_t* w1p = W1 + (size_t)(n0 + l16) * Kdim + quad * 8;
    const ushort_t* w2p = W2 + (size_t)(n0 + l16) * Kdim + quad * 8;
    size_t wstride = (size_t)16 * Kdim;

    for (int k0 = 0; k0 < Kdim; k0 += 32) {
        bf16x8 a1 = *(const bf16x8*)(a1p + k0);
        bf16x8 a2 = *(const bf16x8*)(a2p + k0);
        bf16x8 u0 = *(const bf16x8*)(w1p + k0);
        bf16x8 v0 = *(const bf16x8*)(w2p + k0);
        bf16x8 u1 = *(const bf16x8*)(w1p + wstride + k0);
        bf16x8 v1 = *(const bf16x8*)(w2p + wstride + k0);
        bf16x8 u2 = *(const bf16x8*)(w1p + 2*wstride + k0);
        bf16x8 v2 = *(const bf16x8*)(w2p + 2*wstride + k0);
        bf16x8 u3 = *(const bf16x8*)(w1p + 3*wstride + k0);
        bf16x8 v3 = *(const bf16x8*)(w2p + 3*wstride + k0);
        acc0 = __builtin_amdgcn_mfma_f32_16x16x32_bf16(a1, u0, acc0, 0, 0, 0);
        acc0 = __builtin_amdgcn_mfma_f32_16x16x32_bf16(a2, v0, acc0, 0, 0, 0);
        acc1 = __builtin_amdgcn_mfma_f32_16x16x32_bf16(a1, u1, acc1, 0, 0, 0);
        acc1 = __builtin_amdgcn_mfma_f32_16x16x32_bf16(a2, v1, acc1, 0, 0, 0);
        acc2 = __builtin_amdgcn_mfma_f32_16x16x32_bf16(a1, u2, acc2, 0, 0, 0);
        acc2 = __builtin_amdgcn_mfma_f32_16x16x32_bf16(a2, v2, acc2, 0, 0, 0);
        acc3 = __builtin_amdgcn_mfma_f32_16x16x32_bf16(a1, u3, acc3, 0, 0, 0);
        acc3 = __builtin_amdgcn_mfma_f32_16x16x32_bf16(a2, v3, acc3, 0, 0, 0);
    }

    f32x4 accs[4] = {acc0, acc1, acc2, acc3};
#pragma unroll
    for (int nt = 0; nt < 4; ++nt) {
        int n = n0 + nt * 16 + l16;
        float bb = bias[n];
#pragma unroll
        for (int r = 0; r < 4; ++r) {
            float v = accs[nt][r] + bb;
            if (relu) v = fmaxf(v, 0.f);
            int m = ms + quad * 4 + r;
            if (mode == 1) {
                outp[(size_t)m * Ndim + n] = f2bf(v);
            } else {
                ushort_t hi = f2bf(v);
                float hv = bf2f(hi);
                outp[(size_t)m * Ndim + n]  = hi;
                outp2[(size_t)m * Ndim + n] = f2bf(v - hv);
            }
        }
    }
}

// ---------------- final Gram via split-bf16 MFMA: D = H·H^T, f32 out ----------------
// grid dim3(16,16,16), 256 threads (4 waves); wave = 16-row n-strip, 64-col m-tile.
__global__ __launch_bounds__(256) void final_mfma(const ushort_t* __restrict__ Hhi,
                                                  const ushort_t* __restrict__ Hlo,
                                                  float* __restrict__ out) {
    int tid = threadIdx.x;
    int wave = tid >> 6, lane = tid & 63;
    int quad = lane >> 4, l16 = lane & 15;
    int bz = blockIdx.z;
    int nbase = blockIdx.y * 64 + wave * 16;
    int m0 = blockIdx.x * 64;
    const ushort_t* Hbh = Hhi + (size_t)bz * NPTS * 64;
    const ushort_t* Hbl = Hlo + (size_t)bz * NPTS * 64;

    f32x4 acc[4] = {{0.f,0.f,0.f,0.f},{0.f,0.f,0.f,0.f},{0.f,0.f,0.f,0.f},{0.f,0.f,0.f,0.f}};
    const ushort_t* aph = Hbh + (size_t)(nbase + l16) * 64 + quad * 8;
    const ushort_t* apl = Hbl + (size_t)(nbase + l16) * 64 + quad * 8;
    const ushort_t* bph = Hbh + (size_t)(m0 + l16) * 64 + quad * 8;
    const ushort_t* bpl = Hbl + (size_t)(m0 + l16) * 64 + quad * 8;

#pragma unroll
    for (int k0 = 0; k0 < 64; k0 += 32) {
        bf16x8 ah = *(const bf16x8*)(aph + k0);
        bf16x8 al = *(const bf16x8*)(apl + k0);
#pragma unroll
        for (int nt = 0; nt < 4; ++nt) {
            bf16x8 bh = *(const bf16x8*)(bph + (size_t)nt * 16 * 64 + k0);
            bf16x8 bl = *(const bf16x8*)(bpl + (size_t)nt * 16 * 64 + k0);
            acc[nt] = __builtin_amdgcn_mfma_f32_16x16x32_bf16(ah, bh, acc[nt], 0, 0, 0);
            acc[nt] = __builtin_amdgcn_mfma_f32_16x16x32_bf16(ah, bl, acc[nt], 0, 0, 0);
            acc[nt] = __builtin_amdgcn_mfma_f32_16x16x32_bf16(al, bh, acc[nt], 0, 0, 0);
        }
    }
#pragma unroll
    for (int nt = 0; nt < 4; ++nt) {
#pragma unroll
        for (int r = 0; r < 4; ++r) {
            int n = nbase + quad * 4 + r;
            int m = m0 + nt * 16 + l16;
            out[((size_t)(bz * NPTS + n)) * NPTS + m] = acc[nt][r];
        }
    }
}

// ---------------- launch ----------------
extern "C" void kernel_launch(void* const* d_in, const int* in_sizes, int n_in,
                              void* d_out, int out_size, void* d_ws, size_t ws_size,
                              hipStream_t stream) {
    const float* x = (const float*)d_in[0];
    const float* W[12];
    for (int i = 0; i < 12; ++i) W[i] = (const float*)d_in[1 + i];
    float* out = (float*)d_out;

    // d_ws (~5.5 MB, proven safe): h4 hi/lo + graph structs
    char* w = (char*)d_ws;
    ushort_t* h4hi = (ushort_t*)w; w += (size_t)NODES * 64 * 2;     // 2 MB
    ushort_t* h4lo = (ushort_t*)w; w += (size_t)NODES * 64 * 2;     // 2 MB
    int* nbors  = (int*)w;    w += (size_t)EDGES * 4;               // 640 KB
    int* cnt    = (int*)w;    w += (size_t)NODES * 4;               // 64 KB
    int* cur    = (int*)w;    w += (size_t)NODES * 4;               // 64 KB
    int* rs     = (int*)w;    w += (size_t)(NODES + 1) * 4 + 12;    // 64 KB
    int* esrc   = (int*)w;    w += (size_t)EDGES * 4;               // 640 KB

    // scratch inside d_out (64 MB, fully overwritten by final_mfma):
    char* ob = (char*)d_out;
    ushort_t* aggb  = (ushort_t*)(ob + 0);                   // 8 MB (bf16 agg)
    ushort_t* h1b   = (ushort_t*)(ob + (size_t) 8u*1048576); // 4 MB
    ushort_t* h2b   = (ushort_t*)(ob + (size_t)12u*1048576); // 8 MB
    ushort_t* h3b   = (ushort_t*)(ob + (size_t)20u*1048576); // 8 MB
    float*    agg0f = (float*)   (ob + (size_t)28u*1048576); // 1 MB (f32 agg, din=16)
    ushort_t* wb    = (ushort_t*)(ob + (size_t)29u*1048576); // 448 KB bf16 weights
    float*    pd    = (float*)   (ob + (size_t)30u*1048576); // 10.5 MB (JCH=16)
    int*      pi_   = (int*)     (ob + (size_t)41u*1048576); // 10.5 MB

    cast_weights<<<896, 256, 0, stream>>>(W[3], W[4], W[6], W[7], W[9], W[10], wb);
    knn_partial<<<dim3(JCH, 4, BATCH), 256, 0, stream>>>(x, pd, pi_);
    knn_merge<<<256, 64, 0, stream>>>(pd, pi_, nbors, cnt);   // also zeroes cnt+cur
    count_kernel<<<EDGES / 256, 256, 0, stream>>>(nbors, cnt);
    scan_kernel<<<1, 256, 0, stream>>>(cnt, rs);
    fill_kernel<<<EDGES / 256, 256, 0, stream>>>(nbors, rs, cur, esrc);

    // layer 0: K=16, N=128, f32 compute, bf16 out
    agg_kernel<<<NODES * 4 / 256, 256, 0, stream>>>(x, agg0f, rs, esrc, 16, 2);
    gemm_layer0<<<dim3(2, 256), 256, 0, stream>>>(x, agg0f, W[0], W[1], W[2], h1b, 16, 128);
    // layer 1: K=128, N=256, MFMA
    agg_bf16<<<NODES * 32 / 256, 256, 0, stream>>>(h1b, aggb, rs, esrc, 128, 5);
    gemm_mfma<<<dim3(4, 256), 256, 0, stream>>>(h1b, aggb, wb, wb + 32768, W[5],
                                                h2b, nullptr, 128, 256, 1, 1);
    // layer 2: K=256, N=256, MFMA
    agg_bf16<<<NODES * 64 / 256, 256, 0, stream>>>(h2b, aggb, rs, esrc, 256, 6);
    gemm_mfma<<<dim3(4, 256), 256, 0, stream>>>(h2b, aggb, wb + 65536, wb + 131072, W[8],
                                                h3b, nullptr, 256, 256, 1, 1);
    // layer 3: K=256, N=64, MFMA, no relu, split hi/lo out
    agg_bf16<<<NODES * 64 / 256, 256, 0, stream>>>(h3b, aggb, rs, esrc, 256, 6);
    gemm_mfma<<<dim3(1, 256), 256, 0, stream>>>(h3b, aggb, wb + 196608, wb + 212992, W[11],
                                                h4hi, h4lo, 256, 64, 0, 2);

    final_mfma<<<dim3(16, 16, 16), 256, 0, stream>>>(h4hi, h4lo, out);
}

// Round 9
// 415.093 us; speedup vs baseline: 1.0977x; 1.0977x over previous
//
#include <hip/hip_runtime.h>

#define BATCH 16
#define NPTS 1024
#define CIN 16
#define NODES (BATCH*NPTS)      // 16384
#define KNN 10
#define EDGES (NODES*KNN)       // 163840
#define JCH 16                  // j-chunks for KNN
#define JLEN (NPTS/JCH)         // 64

typedef unsigned short ushort_t;
typedef __attribute__((ext_vector_type(8))) short bf16x8;
typedef __attribute__((ext_vector_type(8))) unsigned short u16x8;
typedef __attribute__((ext_vector_type(4))) float f32x4;

__device__ __forceinline__ int uclamp(int v, int hi) {
    return ((unsigned)v > (unsigned)hi) ? hi : v;
}
__device__ __forceinline__ float bf2f(ushort_t u) {
    union { unsigned int i; float f; } v; v.i = ((unsigned int)u) << 16; return v.f;
}
__device__ __forceinline__ ushort_t f2bf(float f) {
    union { float f; unsigned int i; } v; v.f = f;
    unsigned int r = (v.i + 0x7fffu + ((v.i >> 16) & 1u)) >> 16;
    return (ushort_t)r;
}

// ---------------- cast layer-1..3 weights f32 -> bf16 (229376 elems) ----------------
__global__ __launch_bounds__(256) void cast_weights(const float* __restrict__ s0,
                                                    const float* __restrict__ s1,
                                                    const float* __restrict__ s2,
                                                    const float* __restrict__ s3,
                                                    const float* __restrict__ s4,
                                                    const float* __restrict__ s5,
                                                    ushort_t* __restrict__ dst) {
    int t = blockIdx.x * 256 + threadIdx.x;   // 896 blocks
    const float* s; int off;
    if      (t <  32768) { s = s0; off = 0; }
    else if (t <  65536) { s = s1; off = 32768; }
    else if (t < 131072) { s = s2; off = 65536; }
    else if (t < 196608) { s = s3; off = 131072; }
    else if (t < 212992) { s = s4; off = 196608; }
    else                 { s = s5; off = 212992; }
    dst[t] = f2bf(s[t - off]);
}

// ---------------- KNN phase A: per-(i, j-chunk) top-10, depth-3 parallel insert ----------------
// grid dim3(JCH, 4, BATCH) = 1024 blocks, 256 threads; thread = node i, block covers 64 j's.
__global__ __launch_bounds__(256, 4) void knn_partial(const float* __restrict__ xf,
                                                      float* __restrict__ pd,
                                                      int* __restrict__ pi_) {
    __shared__ float xs[JLEN * 16];   // 4 KB
    __shared__ float sq[JLEN];
    int jc = blockIdx.x, ic = blockIdx.y, b = blockIdx.z;
    int tid = threadIdx.x;
    int i_local = (ic << 8) | tid;
    const float* xbp = xf + (size_t)b * NPTS * CIN;

    const float4* xip = (const float4*)(xbp + i_local * 16);
    float4 xa = xip[0], xb4 = xip[1], xc = xip[2], xd = xip[3];
    float sqi = xa.x*xa.x + xa.y*xa.y + xa.z*xa.z + xa.w*xa.w
              + xb4.x*xb4.x + xb4.y*xb4.y + xb4.z*xb4.z + xb4.w*xb4.w
              + xc.x*xc.x + xc.y*xc.y + xc.z*xc.z + xc.w*xc.w
              + xd.x*xd.x + xd.y*xd.y + xd.z*xd.z + xd.w*xd.w;

    int jbase = jc * JLEN;
    {   // stage 64 rows: thread t stages quarter (t&3) of row (t>>2)
        int row = tid >> 2, q = tid & 3;
        ((float4*)(xs + row * 16))[q] = *(const float4*)(xbp + (jbase + row) * 16 + q * 4);
    }
    __syncthreads();
    if (tid < JLEN) {
        const float4* rp = (const float4*)(xs + tid * 16);
        float4 a = rp[0], bq = rp[1], c4 = rp[2], d4 = rp[3];
        sq[tid] = a.x*a.x + a.y*a.y + a.z*a.z + a.w*a.w
                + bq.x*bq.x + bq.y*bq.y + bq.z*bq.z + bq.w*bq.w
                + c4.x*c4.x + c4.y*c4.y + c4.z*c4.z + c4.w*c4.w
                + d4.x*d4.x + d4.y*d4.y + d4.z*d4.z + d4.w*d4.w;
    }
    __syncthreads();

    float bd[10]; int bi[10];
#pragma unroll
    for (int r = 0; r < 10; ++r) { bd[r] = 3.0e38f; bi[r] = 0; }

#pragma unroll 2
    for (int jl = 0; jl < JLEN; ++jl) {
        const float4* yp = (const float4*)(xs + jl * 16);
        float4 ya = yp[0], yb = yp[1], yc = yp[2], yd = yp[3];
        float d0 = ya.x*xa.x  + ya.y*xa.y  + ya.z*xa.z  + ya.w*xa.w;
        float d1 = yb.x*xb4.x + yb.y*xb4.y + yb.z*xb4.z + yb.w*xb4.w;
        float d2 = yc.x*xc.x  + yc.y*xc.y  + yc.z*xc.z  + yc.w*xc.w;
        float d3 = yd.x*xd.x  + yd.y*xd.y  + yd.z*xd.z  + yd.w*xd.w;
        float dot = (d0 + d1) + (d2 + d3);
        int j = jbase + jl;
        float dist = (sqi + sq[jl]) - 2.0f * dot;
        float c = (j != i_local) ? dist : 3.0e38f;
        int cj = j;
        bool m[10];
#pragma unroll
        for (int k = 0; k < 10; ++k) m[k] = c < bd[k];
        float nbd[10]; int nbi[10];
        nbd[0] = fminf(c, bd[0]);
        nbi[0] = m[0] ? cj : bi[0];
#pragma unroll
        for (int k = 1; k < 10; ++k) {
            nbd[k] = fminf(fmaxf(c, bd[k-1]), bd[k]);   // med3(c, bd[k-1], bd[k])
            nbi[k] = m[k] ? (m[k-1] ? bi[k-1] : cj) : bi[k];
        }
#pragma unroll
        for (int k = 0; k < 10; ++k) { bd[k] = nbd[k]; bi[k] = nbi[k]; }
    }
    int base = (((b * JCH + jc) * NPTS) + i_local) * 10;
#pragma unroll
    for (int r = 0; r < 10; ++r) { pd[base + r] = bd[r]; pi_[base + r] = bi[r]; }
}

// ---------------- KNN phase B: lane-parallel merge, 16 lanes per node ----------------
// 1024 blocks x 256 threads; lane l of a 16-lane group owns sorted list jc=l.
// 10 extract-min rounds via shfl_xor reduction; tie-break (dist, lane asc) == sequential order.
__global__ __launch_bounds__(256) void knn_merge(const float* __restrict__ pd,
                                                 const int* __restrict__ pi_,
                                                 int* __restrict__ nbors,
                                                 int* __restrict__ cntz) {
    int tid = blockIdx.x * 256 + threadIdx.x;     // 0..262143
    if (tid < 32768) cntz[tid] = 0;               // fold-in: zero cnt+cur
    int node = tid >> 4;                          // 0..16383
    int sub  = tid & 15;                          // list index (jc)
    int b = node >> 10, i = node & 1023;
    int lane = threadIdx.x & 63;

    int base = (((b * JCH + sub) * NPTS) + i) * 10;
    float d[11]; int id[10];
    {   // bulk-load my sorted list: 5x float2 + 5x int2 (base is even -> 8B aligned)
        const float2* dp = (const float2*)(pd + base);
        const int2*   ip = (const int2*)(pi_ + base);
#pragma unroll
        for (int q = 0; q < 5; ++q) {
            float2 dv = dp[q]; int2 iv = ip[q];
            d[2*q] = dv.x; d[2*q+1] = dv.y;
            id[2*q] = iv.x; id[2*q+1] = iv.y;
        }
        d[10] = 3.0e38f;
    }

    int res[10];
#pragma unroll
    for (int r = 0; r < 10; ++r) {
        float hd = d[0]; int hl = sub;
        // min over the 16-lane group (xor masks 1,2,4,8 stay in-group)
#pragma unroll
        for (int mk = 1; mk <= 8; mk <<= 1) {
            float od = __shfl_xor(hd, mk, 64);
            int   ol = __shfl_xor(hl, mk, 64);
            bool take = (od < hd) || (od == hd && ol < hl);
            hd = take ? od : hd;
            hl = take ? ol : hl;
        }
        // fetch winner's head index
        int src = (lane & 48) | hl;
        res[r] = __shfl(id[0], src, 64);
        // winner advances its list (predicated shift)
        bool win = (sub == hl);
#pragma unroll
        for (int k = 0; k < 9; ++k) {
            d[k]  = win ? d[k+1]  : d[k];
            id[k] = win ? id[k+1] : id[k];
        }
        d[9] = win ? d[10] : d[9];
    }

    if (sub == 0) {
        int gi = b * NPTS + i;
#pragma unroll
        for (int r = 0; r < 10; ++r)
            nbors[gi * KNN + r] = b * NPTS + uclamp(res[r], NPTS - 1);
    }
}

// ---------------- reverse-CSR build ----------------
__global__ __launch_bounds__(256) void count_kernel(const int* __restrict__ nbors,
                                                    int* __restrict__ cnt) {
    int e = blockIdx.x * 256 + threadIdx.x;
    if (e < EDGES) atomicAdd(&cnt[uclamp(nbors[e], NODES - 1)], 1);
}

__global__ __launch_bounds__(256) void scan_kernel(const int* __restrict__ cnt,
                                                   int* __restrict__ rs) {
    __shared__ int part[256];
    int t = threadIdx.x;
    int base = t << 6;
    int s = 0;
    for (int u = 0; u < 64; ++u) s += cnt[base + u];
    part[t] = s;
    __syncthreads();
    for (int off = 1; off < 256; off <<= 1) {
        int v = (t >= off) ? part[t - off] : 0;
        __syncthreads();
        part[t] += v;
        __syncthreads();
    }
    int run = part[t] - s;
    for (int u = 0; u < 64; ++u) { rs[base + u] = run; run += cnt[base + u]; }
    if (t == 255) rs[NODES] = run;
}

__global__ __launch_bounds__(256) void fill_kernel(const int* __restrict__ nbors,
                                                   const int* __restrict__ rs,
                                                   int* __restrict__ cur,
                                                   int* __restrict__ esrc) {
    int e = blockIdx.x * 256 + threadIdx.x;
    if (e < EDGES) {
        int dst = uclamp(nbors[e], NODES - 1);
        int src = e / 10;
        int pos = atomicAdd(&cur[dst], 1);
        esrc[uclamp(rs[dst] + pos, EDGES - 1)] = src;
    }
}

// ---------------- aggregation f32 (layer 0, din=16) ----------------
__global__ __launch_bounds__(256) void agg_kernel(const float* __restrict__ hin,
                                                  float* __restrict__ agg,
                                                  const int* __restrict__ rs,
                                                  const int* __restrict__ esrc,
                                                  int din, int sh) {
    int gid = blockIdx.x * 256 + threadIdx.x;
    int n = gid >> sh;
    int c = (gid & ((1 << sh) - 1)) << 2;
    int e1 = uclamp(rs[n + 1], EDGES);
    int e0 = uclamp(rs[n], e1);
    float4 acc = {0.f, 0.f, 0.f, 0.f};
    for (int e = e0; e < e1; ++e) {
        int s = uclamp(esrc[e], NODES - 1);
        float4 v = *(const float4*)(hin + (size_t)s * din + c);
        acc.x += v.x; acc.y += v.y; acc.z += v.z; acc.w += v.w;
    }
    *(float4*)(agg + (size_t)n * din + c) = acc;
}

// ---------------- aggregation bf16 (layers 1-3), 16-byte gathers ----------------
// sh = log2(din/8); thread handles 8 channels.
__global__ __launch_bounds__(256) void agg_bf16(const ushort_t* __restrict__ hin,
                                                ushort_t* __restrict__ agg,
                                                const int* __restrict__ rs,
                                                const int* __restrict__ esrc,
                                                int din, int sh) {
    int gid = blockIdx.x * 256 + threadIdx.x;
    int n = gid >> sh;
    int c = (gid & ((1 << sh) - 1)) << 3;
    int e1 = uclamp(rs[n + 1], EDGES);
    int e0 = uclamp(rs[n], e1);
    float a[8] = {0.f,0.f,0.f,0.f,0.f,0.f,0.f,0.f};
    for (int e = e0; e < e1; ++e) {
        int s = uclamp(esrc[e], NODES - 1);
        u16x8 v = *(const u16x8*)(hin + (size_t)s * din + c);
#pragma unroll
        for (int k = 0; k < 8; ++k) a[k] += bf2f(v[k]);
    }
    u16x8 o;
#pragma unroll
    for (int k = 0; k < 8; ++k) o[k] = f2bf(a[k]);
    *(u16x8*)(agg + (size_t)n * din + c) = o;
}

// ---------------- layer-0 GEMM (f32 vector, K=16), bf16 out ----------------
__global__ __launch_bounds__(256) void gemm_layer0(const float* __restrict__ A1,
                                                   const float* __restrict__ A2,
                                                   const float* __restrict__ W1,
                                                   const float* __restrict__ W2,
                                                   const float* __restrict__ bias,
                                                   ushort_t* __restrict__ Out,
                                                   int Kdim, int Ndim) {
    __shared__ float As1[16 * 64], As2[16 * 64], Bs1[16 * 64], Bs2[16 * 64];
    int tid = threadIdx.x;
    int m0 = blockIdx.y * 64;
    int n0 = blockIdx.x * 64;
    int tx = tid & 15, ty = tid >> 4;
    int lr = tid >> 2;
    int lc = (tid & 3) << 2;
    float acc[4][4] = {};

    for (int k0 = 0; k0 < Kdim; k0 += 16) {
        __syncthreads();
        {
            float4 a = *(const float4*)(A1 + (size_t)(m0 + lr) * Kdim + k0 + lc);
            As1[(lc + 0) * 64 + lr] = a.x; As1[(lc + 1) * 64 + lr] = a.y;
            As1[(lc + 2) * 64 + lr] = a.z; As1[(lc + 3) * 64 + lr] = a.w;
            float4 b = *(const float4*)(A2 + (size_t)(m0 + lr) * Kdim + k0 + lc);
            As2[(lc + 0) * 64 + lr] = b.x; As2[(lc + 1) * 64 + lr] = b.y;
            As2[(lc + 2) * 64 + lr] = b.z; As2[(lc + 3) * 64 + lr] = b.w;
            float4 w1 = *(const float4*)(W1 + (size_t)(n0 + lr) * Kdim + k0 + lc);
            Bs1[(lc + 0) * 64 + lr] = w1.x; Bs1[(lc + 1) * 64 + lr] = w1.y;
            Bs1[(lc + 2) * 64 + lr] = w1.z; Bs1[(lc + 3) * 64 + lr] = w1.w;
            float4 w2 = *(const float4*)(W2 + (size_t)(n0 + lr) * Kdim + k0 + lc);
            Bs2[(lc + 0) * 64 + lr] = w2.x; Bs2[(lc + 1) * 64 + lr] = w2.y;
            Bs2[(lc + 2) * 64 + lr] = w2.z; Bs2[(lc + 3) * 64 + lr] = w2.w;
        }
        __syncthreads();
#pragma unroll
        for (int k = 0; k < 16; ++k) {
            float4 a1 = *(const float4*)(As1 + k * 64 + (ty << 2));
            float4 a2 = *(const float4*)(As2 + k * 64 + (ty << 2));
            float4 b1 = *(const float4*)(Bs1 + k * 64 + (tx << 2));
            float4 b2 = *(const float4*)(Bs2 + k * 64 + (tx << 2));
            float av1[4] = {a1.x, a1.y, a1.z, a1.w};
            float av2[4] = {a2.x, a2.y, a2.z, a2.w};
            float bv1[4] = {b1.x, b1.y, b1.z, b1.w};
            float bv2[4] = {b2.x, b2.y, b2.z, b2.w};
#pragma unroll
            for (int u = 0; u < 4; ++u)
#pragma unroll
                for (int v = 0; v < 4; ++v)
                    acc[u][v] += av1[u] * bv1[v] + av2[u] * bv2[v];
        }
    }
    float bv[4];
#pragma unroll
    for (int v = 0; v < 4; ++v) bv[v] = bias[n0 + (tx << 2) + v];
#pragma unroll
    for (int u = 0; u < 4; ++u) {
        int m = m0 + (ty << 2) + u;
        ushort4 o;
        o.x = f2bf(fmaxf(acc[u][0] + bv[0], 0.f));
        o.y = f2bf(fmaxf(acc[u][1] + bv[1], 0.f));
        o.z = f2bf(fmaxf(acc[u][2] + bv[2], 0.f));
        o.w = f2bf(fmaxf(acc[u][3] + bv[3], 0.f));
        *(ushort4*)(Out + (size_t)m * Ndim + n0 + (tx << 2)) = o;
    }
}

// ---------------- MFMA dual-GEMM (layers 1-3) ----------------
__global__ __launch_bounds__(256) void gemm_mfma(const ushort_t* __restrict__ A1,
                                                 const ushort_t* __restrict__ A2,
                                                 const ushort_t* __restrict__ W1,
                                                 const ushort_t* __restrict__ W2,
                                                 const float* __restrict__ bias,
                                                 ushort_t* __restrict__ outp,
                                                 ushort_t* __restrict__ outp2,
                                                 int Kdim, int Ndim, int relu, int mode) {
    int tid = threadIdx.x;
    int wave = tid >> 6, lane = tid & 63;
    int quad = lane >> 4, l16 = lane & 15;
    int ms = blockIdx.y * 64 + wave * 16;
    int n0 = blockIdx.x * 64;

    f32x4 acc0 = {0.f,0.f,0.f,0.f}, acc1 = acc0, acc2 = acc0, acc3 = acc0;
    const ushort_t* a1p = A1 + (size_t)(ms + l16) * Kdim + quad * 8;
    const ushort_t* a2p = A2 + (size_t)(ms + l16) * Kdim + quad * 8;
    const ushort_t* w1p = W1 + (size_t)(n0 + l16) * Kdim + quad * 8;
    const ushort_t* w2p = W2 + (size_t)(n0 + l16) * Kdim + quad * 8;
    size_t wstride = (size_t)16 * Kdim;

    for (int k0 = 0; k0 < Kdim; k0 += 32) {
        bf16x8 a1 = *(const bf16x8*)(a1p + k0);
        bf16x8 a2 = *(const bf16x8*)(a2p + k0);
        bf16x8 u0 = *(const bf16x8*)(w1p + k0);
        bf16x8 v0 = *(const bf16x8*)(w2p + k0);
        bf16x8 u1 = *(const bf16x8*)(w1p + wstride + k0);
        bf16x8 v1 = *(const bf16x8*)(w2p + wstride + k0);
        bf16x8 u2 = *(const bf16x8*)(w1p + 2*wstride + k0);
        bf16x8 v2 = *(const bf16x8*)(w2p + 2*wstride + k0);
        bf16x8 u3 = *(const bf16x8*)(w1p + 3*wstride + k0);
        bf16x8 v3 = *(const bf16x8*)(w2p + 3*wstride + k0);
        acc0 = __builtin_amdgcn_mfma_f32_16x16x32_bf16(a1, u0, acc0, 0, 0, 0);
        acc0 = __builtin_amdgcn_mfma_f32_16x16x32_bf16(a2, v0, acc0, 0, 0, 0);
        acc1 = __builtin_amdgcn_mfma_f32_16x16x32_bf16(a1, u1, acc1, 0, 0, 0);
        acc1 = __builtin_amdgcn_mfma_f32_16x16x32_bf16(a2, v1, acc1, 0, 0, 0);
        acc2 = __builtin_amdgcn_mfma_f32_16x16x32_bf16(a1, u2, acc2, 0, 0, 0);
        acc2 = __builtin_amdgcn_mfma_f32_16x16x32_bf16(a2, v2, acc2, 0, 0, 0);
        acc3 = __builtin_amdgcn_mfma_f32_16x16x32_bf16(a1, u3, acc3, 0, 0, 0);
        acc3 = __builtin_amdgcn_mfma_f32_16x16x32_bf16(a2, v3, acc3, 0, 0, 0);
    }

    f32x4 accs[4] = {acc0, acc1, acc2, acc3};
#pragma unroll
    for (int nt = 0; nt < 4; ++nt) {
        int n = n0 + nt * 16 + l16;
        float bb = bias[n];
#pragma unroll
        for (int r = 0; r < 4; ++r) {
            float v = accs[nt][r] + bb;
            if (relu) v = fmaxf(v, 0.f);
            int m = ms + quad * 4 + r;
            if (mode == 1) {
                outp[(size_t)m * Ndim + n] = f2bf(v);
            } else {
                ushort_t hi = f2bf(v);
                float hv = bf2f(hi);
                outp[(size_t)m * Ndim + n]  = hi;
                outp2[(size_t)m * Ndim + n] = f2bf(v - hv);
            }
        }
    }
}

// ---------------- final Gram via split-bf16 MFMA: D = H·H^T, f32 out ----------------
__global__ __launch_bounds__(256) void final_mfma(const ushort_t* __restrict__ Hhi,
                                                  const ushort_t* __restrict__ Hlo,
                                                  float* __restrict__ out) {
    int tid = threadIdx.x;
    int wave = tid >> 6, lane = tid & 63;
    int quad = lane >> 4, l16 = lane & 15;
    int bz = blockIdx.z;
    int nbase = blockIdx.y * 64 + wave * 16;
    int m0 = blockIdx.x * 64;
    const ushort_t* Hbh = Hhi + (size_t)bz * NPTS * 64;
    const ushort_t* Hbl = Hlo + (size_t)bz * NPTS * 64;

    f32x4 acc[4] = {{0.f,0.f,0.f,0.f},{0.f,0.f,0.f,0.f},{0.f,0.f,0.f,0.f},{0.f,0.f,0.f,0.f}};
    const ushort_t* aph = Hbh + (size_t)(nbase + l16) * 64 + quad * 8;
    const ushort_t* apl = Hbl + (size_t)(nbase + l16) * 64 + quad * 8;
    const ushort_t* bph = Hbh + (size_t)(m0 + l16) * 64 + quad * 8;
    const ushort_t* bpl = Hbl + (size_t)(m0 + l16) * 64 + quad * 8;

#pragma unroll
    for (int k0 = 0; k0 < 64; k0 += 32) {
        bf16x8 ah = *(const bf16x8*)(aph + k0);
        bf16x8 al = *(const bf16x8*)(apl + k0);
#pragma unroll
        for (int nt = 0; nt < 4; ++nt) {
            bf16x8 bh = *(const bf16x8*)(bph + (size_t)nt * 16 * 64 + k0);
            bf16x8 bl = *(const bf16x8*)(bpl + (size_t)nt * 16 * 64 + k0);
            acc[nt] = __builtin_amdgcn_mfma_f32_16x16x32_bf16(ah, bh, acc[nt], 0, 0, 0);
            acc[nt] = __builtin_amdgcn_mfma_f32_16x16x32_bf16(ah, bl, acc[nt], 0, 0, 0);
            acc[nt] = __builtin_amdgcn_mfma_f32_16x16x32_bf16(al, bh, acc[nt], 0, 0, 0);
        }
    }
#pragma unroll
    for (int nt = 0; nt < 4; ++nt) {
#pragma unroll
        for (int r = 0; r < 4; ++r) {
            int n = nbase + quad * 4 + r;
            int m = m0 + nt * 16 + l16;
            out[((size_t)(bz * NPTS + n)) * NPTS + m] = acc[nt][r];
        }
    }
}

// ---------------- launch ----------------
extern "C" void kernel_launch(void* const* d_in, const int* in_sizes, int n_in,
                              void* d_out, int out_size, void* d_ws, size_t ws_size,
                              hipStream_t stream) {
    const float* x = (const float*)d_in[0];
    const float* W[12];
    for (int i = 0; i < 12; ++i) W[i] = (const float*)d_in[1 + i];
    float* out = (float*)d_out;

    // d_ws (~5.5 MB): h4 hi/lo + graph structs
    char* w = (char*)d_ws;
    ushort_t* h4hi = (ushort_t*)w; w += (size_t)NODES * 64 * 2;     // 2 MB
    ushort_t* h4lo = (ushort_t*)w; w += (size_t)NODES * 64 * 2;     // 2 MB
    int* nbors  = (int*)w;    w += (size_t)EDGES * 4;               // 640 KB
    int* cnt    = (int*)w;    w += (size_t)NODES * 4;               // 64 KB
    int* cur    = (int*)w;    w += (size_t)NODES * 4;               // 64 KB
    int* rs     = (int*)w;    w += (size_t)(NODES + 1) * 4 + 12;    // 64 KB
    int* esrc   = (int*)w;    w += (size_t)EDGES * 4;               // 640 KB

    // scratch inside d_out (64 MB, fully overwritten by final_mfma):
    char* ob = (char*)d_out;
    ushort_t* aggb  = (ushort_t*)(ob + 0);                   // 8 MB (bf16 agg)
    ushort_t* h1b   = (ushort_t*)(ob + (size_t) 8u*1048576); // 4 MB
    ushort_t* h2b   = (ushort_t*)(ob + (size_t)12u*1048576); // 8 MB
    ushort_t* h3b   = (ushort_t*)(ob + (size_t)20u*1048576); // 8 MB
    float*    agg0f = (float*)   (ob + (size_t)28u*1048576); // 1 MB (f32 agg, din=16)
    ushort_t* wb    = (ushort_t*)(ob + (size_t)29u*1048576); // 448 KB bf16 weights
    float*    pd    = (float*)   (ob + (size_t)30u*1048576); // 10.5 MB (JCH=16)
    int*      pi_   = (int*)     (ob + (size_t)41u*1048576); // 10.5 MB

    cast_weights<<<896, 256, 0, stream>>>(W[3], W[4], W[6], W[7], W[9], W[10], wb);
    knn_partial<<<dim3(JCH, 4, BATCH), 256, 0, stream>>>(x, pd, pi_);
    knn_merge<<<1024, 256, 0, stream>>>(pd, pi_, nbors, cnt);   // also zeroes cnt+cur
    count_kernel<<<EDGES / 256, 256, 0, stream>>>(nbors, cnt);
    scan_kernel<<<1, 256, 0, stream>>>(cnt, rs);
    fill_kernel<<<EDGES / 256, 256, 0, stream>>>(nbors, rs, cur, esrc);

    // layer 0: K=16, N=128, f32 compute, bf16 out
    agg_kernel<<<NODES * 4 / 256, 256, 0, stream>>>(x, agg0f, rs, esrc, 16, 2);
    gemm_layer0<<<dim3(2, 256), 256, 0, stream>>>(x, agg0f, W[0], W[1], W[2], h1b, 16, 128);
    // layer 1: K=128, N=256, MFMA  (agg 16 threads/node -> sh=4)
    agg_bf16<<<NODES * 16 / 256, 256, 0, stream>>>(h1b, aggb, rs, esrc, 128, 4);
    gemm_mfma<<<dim3(4, 256), 256, 0, stream>>>(h1b, aggb, wb, wb + 32768, W[5],
                                                h2b, nullptr, 128, 256, 1, 1);
    // layer 2: K=256, N=256, MFMA  (32 threads/node -> sh=5)
    agg_bf16<<<NODES * 32 / 256, 256, 0, stream>>>(h2b, aggb, rs, esrc, 256, 5);
    gemm_mfma<<<dim3(4, 256), 256, 0, stream>>>(h2b, aggb, wb + 65536, wb + 131072, W[8],
                                                h3b, nullptr, 256, 256, 1, 1);
    // layer 3: K=256, N=64, MFMA, no relu, split hi/lo out
    agg_bf16<<<NODES * 32 / 256, 256, 0, stream>>>(h3b, aggb, rs, esrc, 256, 5);
    gemm_mfma<<<dim3(1, 256), 256, 0, stream>>>(h3b, aggb, wb + 196608, wb + 212992, W[11],
                                                h4hi, h4lo, 256, 64, 0, 2);

    final_mfma<<<dim3(16, 16, 16), 256, 0, stream>>>(h4hi, h4lo, out);
}